// Round 5
// baseline (7382.446 us; speedup 1.0000x reference)
//
#include <hip/hip_runtime.h>
#include <cstdint>
#include <cstddef>

#define NUSERS 200000
#define NENT   500000
#define NEDGE  2000000
#define NNZV   2000000
#define DIM    64

// ============================================================================
// KEY IDENTITY: l2norm(agg/s) == l2norm(agg) for scalar s>0, so the softmax
// denominator (and max-subtraction) cancel. One fused pass per side per hop:
//   agg[seg] += exp(logit_e) * src_row_e      (unnormalized softmax-weighted sum)
// Unstable exp is safe: hop-1 logits ~N(0,64) -> max ~ +45 << 88 (fp32 exp ovf).
// Pre-norm agg can reach ~1e20 -> l2norm sum-of-squares MUST be double.
// ============================================================================

// ---- fused entity aggregation: 16 lanes/edge, float4; 4 edges per wave ----
//   w = dot(ent[tail], rel[etype-1]) / 8 ;  agg[head] += exp(w) * ent[tail]
__global__ void ent_fused_kernel(const float* __restrict__ ent,
                                 const float* __restrict__ rel,
                                 const int* __restrict__ head,
                                 const int* __restrict__ tail,
                                 const int* __restrict__ etype,
                                 float* __restrict__ agg,
                                 int E)
{
    int idx = blockIdx.x * blockDim.x + threadIdx.x;
    int e   = idx >> 4;   // 16 lanes per edge
    int l   = idx & 15;
    if (e >= E) return;
    int t = tail[e];
    int r = etype[e] - 1;
    int h = head[e];
    float4 ev = ((const float4*)(ent + (size_t)t * DIM))[l];
    float4 rv = ((const float4*)(rel + (size_t)r * DIM))[l];
    float d = ev.x * rv.x + ev.y * rv.y + ev.z * rv.z + ev.w * rv.w;
#pragma unroll
    for (int off = 1; off < 16; off <<= 1) d += __shfl_xor(d, off);  // stays in 16-group
    float ew = __expf(d * 0.125f);
    float* arow = agg + (size_t)h * DIM + l * 4;
    atomicAdd(arow + 0, ev.x * ew);
    atomicAdd(arow + 1, ev.y * ew);
    atomicAdd(arow + 2, ev.z * ew);
    atomicAdd(arow + 3, ev.w * ew);
}

// ---- fused user aggregation: 16 lanes/nnz, float4 ----
//   att = dot(inter[it] * usr[u], ent[item]) ;  agg[u] += exp(att) * ent[item]
__global__ void usr_fused_kernel(const float* __restrict__ ent,
                                 const float* __restrict__ usr,
                                 const float* __restrict__ inter,
                                 const int* __restrict__ uidx,
                                 const int* __restrict__ iidx,
                                 const int* __restrict__ itype,
                                 float* __restrict__ agg,
                                 int E)
{
    int idx = blockIdx.x * blockDim.x + threadIdx.x;
    int e   = idx >> 4;
    int l   = idx & 15;
    if (e >= E) return;
    int u  = uidx[e];
    int im = iidx[e];
    int it = itype[e];
    float4 ev = ((const float4*)(ent   + (size_t)im * DIM))[l];
    float4 uv = ((const float4*)(usr   + (size_t)u  * DIM))[l];
    float4 iv = ((const float4*)(inter + (size_t)it * DIM))[l];
    float d = ev.x * uv.x * iv.x + ev.y * uv.y * iv.y +
              ev.z * uv.z * iv.z + ev.w * uv.w * iv.w;
#pragma unroll
    for (int off = 1; off < 16; off <<= 1) d += __shfl_xor(d, off);
    float ew = __expf(d);
    float* arow = agg + (size_t)u * DIM + l * 4;
    atomicAdd(arow + 0, ev.x * ew);
    atomicAdd(arow + 1, ev.y * ew);
    atomicAdd(arow + 2, ev.z * ew);
    atomicAdd(arow + 3, ev.w * ew);
}

// ---- l2-normalize agg in place (double sum-of-squares!), accumulate into out ----
// 16 lanes/row, float4; 4 rows per wave.
__global__ void norm_res_kernel(float* __restrict__ agg,
                                float* __restrict__ out,
                                int N)
{
    int idx = blockIdx.x * blockDim.x + threadIdx.x;
    int row = idx >> 4;
    int l   = idx & 15;
    if (row >= N) return;
    float4 v = ((const float4*)(agg + (size_t)row * DIM))[l];
    double ss = (double)v.x * v.x + (double)v.y * v.y +
                (double)v.z * v.z + (double)v.w * v.w;
#pragma unroll
    for (int off = 1; off < 16; off <<= 1) ss += __shfl_xor(ss, off);
    float inv = (float)(1.0 / fmax(sqrt(ss), 1e-12));
    v.x *= inv; v.y *= inv; v.z *= inv; v.w *= inv;
    ((float4*)(agg + (size_t)row * DIM))[l] = v;
    float4 o = ((const float4*)(out + (size_t)row * DIM))[l];
    o.x += v.x; o.y += v.y; o.z += v.z; o.w += v.w;
    ((float4*)(out + (size_t)row * DIM))[l] = o;
}

extern "C" void kernel_launch(void* const* d_in, const int* in_sizes, int n_in,
                              void* d_out, int out_size, void* d_ws, size_t ws_size,
                              hipStream_t stream)
{
    const float* user_emb     = (const float*)d_in[0];
    const float* entity_emb   = (const float*)d_in[1];
    const float* interact_emb = (const float*)d_in[2];
    const float* relation_emb = (const float*)d_in[3];
    const int*   edge_index   = (const int*)d_in[4];
    const int*   edge_type    = (const int*)d_in[5];
    const int*   user_index   = (const int*)d_in[6];
    const int*   item_index   = (const int*)d_in[7];
    const int*   interact_tp  = (const int*)d_in[8];
    const int* head = edge_index;            // edge_index[0, :]
    const int* tail = edge_index + NEDGE;    // edge_index[1, :]

    // ---- workspace: just the two ping-pong aggregation tables per side ----
    char* ws = (char*)d_ws;
    size_t o = 0;
    const size_t ENT_BYTES = (size_t)NENT * DIM * sizeof(float);
    const size_t USR_BYTES = (size_t)NUSERS * DIM * sizeof(float);
    float* entA = (float*)(ws + o); o += ENT_BYTES;
    float* entB = (float*)(ws + o); o += ENT_BYTES;
    float* usrA = (float*)(ws + o); o += USR_BYTES;
    float* usrB = (float*)(ws + o); o += USR_BYTES;
    if (ws_size < o) return;

    float* out_ent = (float*)d_out;
    float* out_usr = out_ent + (size_t)NENT * DIM;

    // residual accumulators start as the input embeddings
    hipMemcpyAsync(out_ent, entity_emb, ENT_BYTES, hipMemcpyDeviceToDevice, stream);
    hipMemcpyAsync(out_usr, user_emb, USR_BYTES, hipMemcpyDeviceToDevice, stream);

    const int BLK = 256;
    const int edge_blocks = (int)(((size_t)NEDGE * 16 + BLK - 1) / BLK);
    const int nnz_blocks  = (int)(((size_t)NNZV  * 16 + BLK - 1) / BLK);
    const int ent_blocks  = (int)(((size_t)NENT  * 16 + BLK - 1) / BLK);
    const int usr_blocks  = (int)(((size_t)NUSERS* 16 + BLK - 1) / BLK);

    const float* ecur = entity_emb;
    const float* ucur = user_emb;
    float* eaggs[2] = {entA, entB};
    float* uaggs[2] = {usrA, usrB};

    for (int hop = 0; hop < 2; ++hop) {
        float* ea = eaggs[hop];
        float* ua = uaggs[hop];
        hipMemsetAsync(ea, 0, ENT_BYTES, stream);
        hipMemsetAsync(ua, 0, USR_BYTES, stream);

        ent_fused_kernel<<<edge_blocks, BLK, 0, stream>>>(
            ecur, relation_emb, head, tail, edge_type, ea, NEDGE);
        usr_fused_kernel<<<nnz_blocks, BLK, 0, stream>>>(
            ecur, ucur, interact_emb, user_index, item_index, interact_tp,
            ua, NNZV);

        norm_res_kernel<<<ent_blocks, BLK, 0, stream>>>(ea, out_ent, NENT);
        norm_res_kernel<<<usr_blocks, BLK, 0, stream>>>(ua, out_usr, NUSERS);

        ecur = ea;
        ucur = ua;
    }
}

// Round 6
// 1502.478 us; speedup vs baseline: 4.9135x; 4.9135x over previous
//
#include <hip/hip_runtime.h>
#include <cstdint>
#include <cstddef>

#define NUSERS 200000
#define NENT   500000
#define NEDGE  2000000
#define NSEG   (NENT + NUSERS)   // combined segment space: entities then users
#define DIM    64

// ============================================================================
// Softmax-denominator cancellation (verified r5, absmax .016): l2norm(agg/s) ==
// l2norm(agg), so compute unnormalized sum_e exp(logit_e)*row_e.  ss in DOUBLE
// (pre-norm rows reach ~1e19 -> squares overflow fp32).
// This round: NO float atomics.  Build CSR once/call (indices identical across
// hops), then aggregation is gather-only, with l2norm+residual fused in.
// ============================================================================

// ---------- CSR build ----------
__global__ void hist_kernel(const int* __restrict__ head,
                            const int* __restrict__ uidx,
                            int* __restrict__ cnt, int E)
{
    int e = blockIdx.x * blockDim.x + threadIdx.x;
    if (e >= E) return;
    atomicAdd(&cnt[head[e]], 1);
    atomicAdd(&cnt[NENT + uidx[e]], 1);
}

// per-block (1024 elems) exclusive scan; block totals to bsum
__global__ void scan_part_kernel(const int* __restrict__ cnt,
                                 int* __restrict__ off,
                                 int* __restrict__ bsum, int N)
{
    int t = threadIdx.x;
    int base = blockIdx.x * 1024 + t * 4;
    int v0 = (base + 0 < N) ? cnt[base + 0] : 0;
    int v1 = (base + 1 < N) ? cnt[base + 1] : 0;
    int v2 = (base + 2 < N) ? cnt[base + 2] : 0;
    int v3 = (base + 3 < N) ? cnt[base + 3] : 0;
    int ts = v0 + v1 + v2 + v3;
    __shared__ int s[256];
    s[t] = ts;
    __syncthreads();
    for (int d = 1; d < 256; d <<= 1) {
        int x = (t >= d) ? s[t - d] : 0;
        __syncthreads();
        s[t] += x;
        __syncthreads();
    }
    if (t == 255) bsum[blockIdx.x] = s[255];
    int p = (t == 0) ? 0 : s[t - 1];
    if (base + 0 < N) off[base + 0] = p; p += v0;
    if (base + 1 < N) off[base + 1] = p; p += v1;
    if (base + 2 < N) off[base + 2] = p; p += v2;
    if (base + 3 < N) off[base + 3] = p;
}

// single-block exclusive scan of block sums (nb <= 1024)
__global__ void scan_sums_kernel(const int* __restrict__ bsum,
                                 int* __restrict__ boff, int nb)
{
    int t = threadIdx.x;
    int j = t * 4;
    int v0 = (j + 0 < nb) ? bsum[j + 0] : 0;
    int v1 = (j + 1 < nb) ? bsum[j + 1] : 0;
    int v2 = (j + 2 < nb) ? bsum[j + 2] : 0;
    int v3 = (j + 3 < nb) ? bsum[j + 3] : 0;
    int ts = v0 + v1 + v2 + v3;
    __shared__ int s[256];
    s[t] = ts;
    __syncthreads();
    for (int d = 1; d < 256; d <<= 1) {
        int x = (t >= d) ? s[t - d] : 0;
        __syncthreads();
        s[t] += x;
        __syncthreads();
    }
    int p = (t == 0) ? 0 : s[t - 1];
    if (j + 0 < nb) boff[j + 0] = p; p += v0;
    if (j + 1 < nb) boff[j + 1] = p; p += v1;
    if (j + 2 < nb) boff[j + 2] = p; p += v2;
    if (j + 3 < nb) boff[j + 3] = p;
}

__global__ void scan_add_kernel(int* __restrict__ off,
                                int* __restrict__ cur,
                                const int* __restrict__ boff, int N)
{
    int i = blockIdx.x * blockDim.x + threadIdx.x;
    if (i >= N) return;
    int v = off[i] + boff[i >> 10];
    off[i] = v;
    cur[i] = v;   // fill cursor; after fill, cur[seg] == segment end
}

__global__ void fill_kernel(const int* __restrict__ head,
                            const int* __restrict__ uidx,
                            int* __restrict__ cur,
                            int* __restrict__ elist, int E)
{
    int e = blockIdx.x * blockDim.x + threadIdx.x;
    if (e >= E) return;
    int p = atomicAdd(&cur[head[e]], 1);
    elist[p] = e;
    int q = atomicAdd(&cur[NENT + uidx[e]], 1);
    elist[q] = e;
}

// ---------- fused entity aggregation + l2norm + residual ----------
// 16 lanes per entity segment.  agg = sum exp(dot(ent[tail],rel[et-1])/8)*ent[tail]
__global__ void ent_agg_kernel(const float* __restrict__ ecur,
                               const float* __restrict__ rel,
                               const int* __restrict__ tail,
                               const int* __restrict__ etype,
                               const int* __restrict__ off,
                               const int* __restrict__ cur,
                               const int* __restrict__ elist,
                               const float* __restrict__ res_in,
                               float* __restrict__ out,
                               float* __restrict__ enew, int N)
{
    int idx = blockIdx.x * blockDim.x + threadIdx.x;
    int seg = idx >> 4;
    int l   = idx & 15;
    if (seg >= N) return;
    int start = off[seg], end = cur[seg];
    float4 acc = make_float4(0.f, 0.f, 0.f, 0.f);
    for (int j0 = start; j0 < end; j0 += 16) {
        int nk = end - j0; if (nk > 16) nk = 16;
        int tl = 0, rl = 0;
        if (j0 + l < end) {
            int eid = elist[j0 + l];
            tl = tail[eid];
            rl = etype[eid] - 1;
        }
        for (int k = 0; k < nk; ++k) {
            int t = __shfl(tl, k, 16);
            int r = __shfl(rl, k, 16);
            float4 ev = ((const float4*)(ecur + (size_t)t * DIM))[l];
            float4 rv = ((const float4*)(rel  + (size_t)r * DIM))[l];
            float d = ev.x * rv.x + ev.y * rv.y + ev.z * rv.z + ev.w * rv.w;
#pragma unroll
            for (int o2 = 1; o2 < 16; o2 <<= 1) d += __shfl_xor(d, o2);
            float ew = __expf(d * 0.125f);
            acc.x += ev.x * ew; acc.y += ev.y * ew;
            acc.z += ev.z * ew; acc.w += ev.w * ew;
        }
    }
    double ss = (double)acc.x * acc.x + (double)acc.y * acc.y +
                (double)acc.z * acc.z + (double)acc.w * acc.w;
#pragma unroll
    for (int o2 = 1; o2 < 16; o2 <<= 1) ss += __shfl_xor(ss, o2);
    float inv = (float)(1.0 / fmax(sqrt(ss), 1e-12));
    float4 nv = make_float4(acc.x * inv, acc.y * inv, acc.z * inv, acc.w * inv);
    ((float4*)(enew + (size_t)seg * DIM))[l] = nv;
    float4 ri = ((const float4*)(res_in + (size_t)seg * DIM))[l];
    nv.x += ri.x; nv.y += ri.y; nv.z += ri.z; nv.w += ri.w;
    ((float4*)(out + (size_t)seg * DIM))[l] = nv;
}

// ---------- fused user aggregation + l2norm + residual ----------
// att = dot(inter[it]*usr[u], ent[item]);  agg = sum exp(att)*ent[item]
__global__ void usr_agg_kernel(const float* __restrict__ ecur,
                               const float* __restrict__ ucur,
                               const float* __restrict__ inter,
                               const int* __restrict__ iidx,
                               const int* __restrict__ itype,
                               const int* __restrict__ off,
                               const int* __restrict__ cur,
                               const int* __restrict__ elist,
                               const float* __restrict__ res_in,
                               float* __restrict__ out,
                               float* __restrict__ unew, int N)
{
    int idx = blockIdx.x * blockDim.x + threadIdx.x;
    int seg = idx >> 4;      // user id
    int l   = idx & 15;
    if (seg >= N) return;
    int start = off[NENT + seg], end = cur[NENT + seg];
    float4 uv = ((const float4*)(ucur + (size_t)seg * DIM))[l];
    float4 acc = make_float4(0.f, 0.f, 0.f, 0.f);
    for (int j0 = start; j0 < end; j0 += 16) {
        int nk = end - j0; if (nk > 16) nk = 16;
        int il = 0, tl = 0;
        if (j0 + l < end) {
            int eid = elist[j0 + l];
            il = iidx[eid];
            tl = itype[eid];
        }
        for (int k = 0; k < nk; ++k) {
            int im = __shfl(il, k, 16);
            int it = __shfl(tl, k, 16);
            float4 ev = ((const float4*)(ecur  + (size_t)im * DIM))[l];
            float4 iv = ((const float4*)(inter + (size_t)it * DIM))[l];
            float d = ev.x * uv.x * iv.x + ev.y * uv.y * iv.y +
                      ev.z * uv.z * iv.z + ev.w * uv.w * iv.w;
#pragma unroll
            for (int o2 = 1; o2 < 16; o2 <<= 1) d += __shfl_xor(d, o2);
            float ew = __expf(d);
            acc.x += ev.x * ew; acc.y += ev.y * ew;
            acc.z += ev.z * ew; acc.w += ev.w * ew;
        }
    }
    double ss = (double)acc.x * acc.x + (double)acc.y * acc.y +
                (double)acc.z * acc.z + (double)acc.w * acc.w;
#pragma unroll
    for (int o2 = 1; o2 < 16; o2 <<= 1) ss += __shfl_xor(ss, o2);
    float inv = (float)(1.0 / fmax(sqrt(ss), 1e-12));
    float4 nv = make_float4(acc.x * inv, acc.y * inv, acc.z * inv, acc.w * inv);
    ((float4*)(unew + (size_t)seg * DIM))[l] = nv;
    float4 ri = ((const float4*)(res_in + (size_t)seg * DIM))[l];
    nv.x += ri.x; nv.y += ri.y; nv.z += ri.z; nv.w += ri.w;
    ((float4*)(out + (size_t)seg * DIM))[l] = nv;
}

extern "C" void kernel_launch(void* const* d_in, const int* in_sizes, int n_in,
                              void* d_out, int out_size, void* d_ws, size_t ws_size,
                              hipStream_t stream)
{
    const float* user_emb     = (const float*)d_in[0];
    const float* entity_emb   = (const float*)d_in[1];
    const float* interact_emb = (const float*)d_in[2];
    const float* relation_emb = (const float*)d_in[3];
    const int*   edge_index   = (const int*)d_in[4];
    const int*   edge_type    = (const int*)d_in[5];
    const int*   user_index   = (const int*)d_in[6];
    const int*   item_index   = (const int*)d_in[7];
    const int*   interact_tp  = (const int*)d_in[8];
    const int* head = edge_index;            // edge_index[0, :]
    const int* tail = edge_index + NEDGE;    // edge_index[1, :]

    // ---- workspace ----
    char* ws = (char*)d_ws;
    size_t o = 0;
    const size_t ENT_BYTES = (size_t)NENT * DIM * sizeof(float);
    const size_t USR_BYTES = (size_t)NUSERS * DIM * sizeof(float);
    float* entA  = (float*)(ws + o); o += ENT_BYTES;
    float* entB  = (float*)(ws + o); o += ENT_BYTES;
    float* usrA  = (float*)(ws + o); o += USR_BYTES;
    float* usrB  = (float*)(ws + o); o += USR_BYTES;
    int*   cnt   = (int*)(ws + o);   o += (size_t)NSEG * 4;
    int*   off   = (int*)(ws + o);   o += (size_t)NSEG * 4;
    int*   cur   = (int*)(ws + o);   o += (size_t)NSEG * 4;
    int*   elist = (int*)(ws + o);   o += (size_t)2 * NEDGE * 4;
    int*   bsum  = (int*)(ws + o);   o += 1024 * 4;
    int*   boff  = (int*)(ws + o);   o += 1024 * 4;
    if (ws_size < o) return;

    float* out_ent = (float*)d_out;
    float* out_usr = out_ent + (size_t)NENT * DIM;

    const int BLK = 256;
    const int nb_scan = (NSEG + 1023) / 1024;   // 684 <= 1024

    // ---- build CSR (once; indices are hop-invariant) ----
    hipMemsetAsync(cnt, 0, (size_t)NSEG * 4, stream);
    hist_kernel<<<(NEDGE + BLK - 1) / BLK, BLK, 0, stream>>>(head, user_index, cnt, NEDGE);
    scan_part_kernel<<<nb_scan, BLK, 0, stream>>>(cnt, off, bsum, NSEG);
    scan_sums_kernel<<<1, BLK, 0, stream>>>(bsum, boff, nb_scan);
    scan_add_kernel<<<(NSEG + BLK - 1) / BLK, BLK, 0, stream>>>(off, cur, boff, NSEG);
    fill_kernel<<<(NEDGE + BLK - 1) / BLK, BLK, 0, stream>>>(head, user_index, cur, elist, NEDGE);

    const int ent_blocks = (int)(((size_t)NENT * 16 + BLK - 1) / BLK);
    const int usr_blocks = (int)(((size_t)NUSERS * 16 + BLK - 1) / BLK);

    const float* ecur = entity_emb;
    const float* ucur = user_emb;
    float* eaggs[2] = {entA, entB};
    float* uaggs[2] = {usrA, usrB};

    for (int hop = 0; hop < 2; ++hop) {
        float* ea = eaggs[hop];
        float* ua = uaggs[hop];
        const float* res_e = (hop == 0) ? entity_emb : out_ent;
        const float* res_u = (hop == 0) ? user_emb   : out_usr;

        ent_agg_kernel<<<ent_blocks, BLK, 0, stream>>>(
            ecur, relation_emb, tail, edge_type, off, cur, elist,
            res_e, out_ent, ea, NENT);
        usr_agg_kernel<<<usr_blocks, BLK, 0, stream>>>(
            ecur, ucur, interact_emb, item_index, interact_tp, off, cur, elist,
            res_u, out_usr, ua, NUSERS);

        ecur = ea;
        ucur = ua;
    }
}